// Round 9
// baseline (840.499 us; speedup 1.0000x reference)
//
#include <hip/hip_runtime.h>
#include <cstdint>

#define T_TOK 1024
#define HID   2048
#define NEXP  64
#define TOPK  8
#define INTER 768

typedef __attribute__((ext_vector_type(8))) short short8;   // 8 x bf16
typedef __attribute__((ext_vector_type(4))) float f32x4;

__device__ __forceinline__ unsigned short f2bf(float f){
  unsigned u = __float_as_uint(f);
  u += 0x7FFFu + ((u >> 16) & 1u);   // RNE
  return (unsigned short)(u >> 16);
}

// ---------------- kernel 1: x (fp32) -> bf16 once per launch ----------------
__global__ void k_convert_x(const float* __restrict__ x, unsigned short* __restrict__ xbf){
  int gid = blockIdx.x * 256 + threadIdx.x;
  const float4* src = (const float4*)(x + (size_t)gid * 8);
  float4 a = src[0], b = src[1];
  uint4 p;
  p.x = f2bf(a.x) | ((unsigned)f2bf(a.y) << 16);
  p.y = f2bf(a.z) | ((unsigned)f2bf(a.w) << 16);
  p.z = f2bf(b.x) | ((unsigned)f2bf(b.y) << 16);
  p.w = f2bf(b.z) | ((unsigned)f2bf(b.w) << 16);
  *(uint4*)(xbf + (size_t)gid * 8) = p;
}

// ---------------- kernel 2: router (fp32-exact logits, top-8) ----------------
__global__ void k_router(const float* __restrict__ x, const float* __restrict__ gw,
                         int* __restrict__ top_idx, float* __restrict__ top_w){
  int t = blockIdx.x;
  int tid = threadIdx.x;
  __shared__ float  xs[HID];
  __shared__ double part[4][NEXP];
  for (int i = tid; i < HID; i += 256) xs[i] = x[(size_t)t * HID + i];
  __syncthreads();
  int e = tid & 63, q = tid >> 6;
  double acc = 0.0;
  const float* gp = gw + e;
  #pragma unroll 8
  for (int h = q * 512; h < q * 512 + 512; ++h)
    acc += (double)xs[h] * (double)gp[(size_t)h * NEXP];
  part[q][e] = acc;
  __syncthreads();
  if (tid < 64){
    float logit = (float)(part[0][e] + part[1][e] + part[2][e] + part[3][e]);
    float cur = logit;
    float vals[TOPK]; int idxs[TOPK];
    #pragma unroll
    for (int k = 0; k < TOPK; ++k){
      float m = cur; int mi = e;
      #pragma unroll
      for (int off = 32; off > 0; off >>= 1){
        float ov = __shfl_xor(m, off);
        int   oi = __shfl_xor(mi, off);
        if (ov > m || (ov == m && oi < mi)){ m = ov; mi = oi; }
      }
      vals[k] = m; idxs[k] = mi;
      if (e == mi) cur = -1e30f;
    }
    float mx = vals[0], s = 0.f, ev[TOPK];
    #pragma unroll
    for (int k = 0; k < TOPK; ++k){ ev[k] = expf(vals[k] - mx); s += ev[k]; }
    #pragma unroll
    for (int k = 0; k < TOPK; ++k)
      if (e == k){ top_idx[t * TOPK + k] = idxs[k]; top_w[t * TOPK + k] = ev[k] / s; }
  }
}

// ---------------- kernel 3: per-expert histogram + exclusive scan ----------------
__global__ void k_hist(const int* __restrict__ top_idx, int* __restrict__ offs){
  __shared__ int hist[NEXP];
  int tid = threadIdx.x;
  if (tid < NEXP) hist[tid] = 0;
  __syncthreads();
  for (int j = tid; j < T_TOK * TOPK; j += 256) atomicAdd(&hist[top_idx[j]], 1);
  __syncthreads();
  if (tid == 0){
    int run = 0;
    for (int e = 0; e < NEXP; ++e){ offs[e] = run; run += hist[e]; }
    offs[NEXP] = run;
  }
}

// ---------------- kernel 4: deterministic ordered compaction ----------------
__global__ void k_compact(const int* __restrict__ top_idx, const float* __restrict__ top_w,
                          const int* __restrict__ offs, int* __restrict__ list_t,
                          float* __restrict__ list_w, int* __restrict__ slot_of){
  int e = blockIdx.x, tid = threadIdx.x;
  __shared__ int sc[256];
  int j0 = tid * 32, cnt = 0;
  for (int jj = 0; jj < 32; ++jj) cnt += (top_idx[j0 + jj] == e);
  sc[tid] = cnt; __syncthreads();
  for (int d = 1; d < 256; d <<= 1){
    int v = (tid >= d) ? sc[tid - d] : 0;
    __syncthreads();
    sc[tid] += v;
    __syncthreads();
  }
  int pos = offs[e] + sc[tid] - cnt;
  for (int jj = 0; jj < 32; ++jj){
    int j = j0 + jj;
    if (top_idx[j] == e){
      list_t[pos]  = j >> 3;
      list_w[pos]  = top_w[j];
      slot_of[j]   = pos;
      ++pos;
    }
  }
}

#define BARRIER() do { asm volatile("s_waitcnt lgkmcnt(0)" ::: "memory"); \
                       __builtin_amdgcn_s_barrier(); } while (0)

// ---------------- kernel 5: gate/up GEMM + SwiGLU ----------------
// R2 geometry: 512 thr = 8 waves (4m x 2n), BM=192, BN=64 x {gate,up}, BK=64, KT=32.
// Depth-4 B register sets + 2 LDS buffers (write tile T in body T-1; loads issued
// body T-4 => 3-body cover). A 2-ahead (3 sets), issued BEFORE B each body so
// in-order vmcnt drains at MFMA/WRITE never kill the youngest 2 B-tiles.
// NO launch_bounds min-wave (R3 spill lesson). Expert->XCD colocated blocks.
__global__ __launch_bounds__(512) void k_gateup(
    const unsigned short* __restrict__ xbf, const float* __restrict__ wg,
    const float* __restrict__ wu, const int* __restrict__ offs,
    const int* __restrict__ list_t, const float* __restrict__ list_w,
    unsigned short* __restrict__ act){
  int bid = blockIdx.x;                   // 768 = 64 e x 12 ib, XCD-colocated per e
  int xcd = bid & 7, idx = bid >> 3;      // idx 0..95
  int e  = (idx / 12) * 8 + xcd;
  int i0 = (idx % 12) * 64;
  int beg = offs[e], n_e = offs[e + 1] - beg;
  if (n_e <= 0) return;
  int tid = threadIdx.x, lane = tid & 63, wid = tid >> 6;
  int wm = wid & 3, wn = wid >> 2;        // 48-row m-quarter, 32-col n-half

  __shared__ unsigned short lB[2][2][64 * 64];   // [buf][mat][i*64k] swizzled, 32 KB
  __shared__ int   sTok[192];
  __shared__ float sWgt[192];

  int bi = tid & 63, bg = tid >> 6;
  int bswz = (bi & 7) << 4;
  const float* gBase = wg + (size_t)e * HID * INTER + i0 + bi;
  const float* uBase = wu + (size_t)e * HID * INTER + i0 + bi;

#define GU_ISSUE_B(T, rg_, ru_) { \
    const float* _gp = gBase + (size_t)((T) * 64 + bg * 8) * INTER; \
    const float* _up = uBase + (size_t)((T) * 64 + bg * 8) * INTER; \
    _Pragma("unroll") for (int j = 0; j < 8; ++j){ \
      rg_[j] = _gp[(size_t)j * INTER]; ru_[j] = _up[(size_t)j * INTER]; } }

#define GU_WRITE_B(buf, rg_, ru_) { \
    uint4 _p; \
    _p.x = f2bf(rg_[0]) | ((unsigned)f2bf(rg_[1]) << 16); \
    _p.y = f2bf(rg_[2]) | ((unsigned)f2bf(rg_[3]) << 16); \
    _p.z = f2bf(rg_[4]) | ((unsigned)f2bf(rg_[5]) << 16); \
    _p.w = f2bf(rg_[6]) | ((unsigned)f2bf(rg_[7]) << 16); \
    *(uint4*)((char*)&lB[buf][0][0] + bi * 128 + ((bg * 16) ^ bswz)) = _p; \
    _p.x = f2bf(ru_[0]) | ((unsigned)f2bf(ru_[1]) << 16); \
    _p.y = f2bf(ru_[2]) | ((unsigned)f2bf(ru_[3]) << 16); \
    _p.z = f2bf(ru_[4]) | ((unsigned)f2bf(ru_[5]) << 16); \
    _p.w = f2bf(ru_[6]) | ((unsigned)f2bf(ru_[7]) << 16); \
    *(uint4*)((char*)&lB[buf][1][0] + bi * 128 + ((bg * 16) ^ bswz)) = _p; }

#define GU_ISSUE_A(T, ra_) { \
    int _kk = (T) * 64 + ((lane >> 4) << 3); \
    _Pragma("unroll") for (int mf = 0; mf < 3; ++mf){ \
      const unsigned short* _ap = xbf + (size_t)tokA[mf] * HID + _kk; \
      ra_[mf][0] = *(const short8*)_ap; \
      ra_[mf][1] = *(const short8*)(_ap + 32); } }

#define GU_MFMA(buf, ra_) { \
    _Pragma("unroll") for (int ks = 0; ks < 2; ++ks){ \
      short8 _bf[2][2]; \
      _Pragma("unroll") for (int nf = 0; nf < 2; ++nf){ \
        int _il = wn * 32 + nf * 16 + (lane & 15); \
        int _kb = (ks * 64 + ((lane >> 4) << 4)) ^ ((_il & 7) << 4); \
        _bf[0][nf] = *(const short8*)((const char*)&lB[buf][0][0] + _il * 128 + _kb); \
        _bf[1][nf] = *(const short8*)((const char*)&lB[buf][1][0] + _il * 128 + _kb); } \
      _Pragma("unroll") for (int mf = 0; mf < 3; ++mf) \
        _Pragma("unroll") for (int nf = 0; nf < 2; ++nf){ \
          accg[mf][nf] = __builtin_amdgcn_mfma_f32_16x16x32_bf16(ra_[mf][ks], _bf[0][nf], accg[mf][nf], 0, 0, 0); \
          accu[mf][nf] = __builtin_amdgcn_mfma_f32_16x16x32_bf16(ra_[mf][ks], _bf[1][nf], accu[mf][nf], 0, 0, 0); } } }

// body K (K = T mod 12, cycle lcm(4,3,2)=12): A(T+2)->set (K+2)%3 [FIRST];
// B(T+4)->set K%4; MFMA buf K&1 with A-set K%3; WRITE B-set (K+1)%4 -> buf (K+1)&1.
#define GU_BODY(T, K, DA, DB, DW) { \
    if (DA) GU_ISSUE_A((T) + 2, rA[((K) + 2) % 3]); \
    if (DB) GU_ISSUE_B((T) + 4, rg[(K) % 4], ru[(K) % 4]); \
    GU_MFMA((K) & 1, rA[(K) % 3]); \
    if (DW) GU_WRITE_B(((K) + 1) & 1, rg[((K) + 1) % 4], ru[((K) + 1) % 4]); \
    BARRIER(); }

  for (int m0 = 0; m0 < n_e; m0 += 192){
    __syncthreads();
    if (tid < 192){
      int sl = beg + m0 + tid;
      if (m0 + tid < n_e){ sTok[tid] = list_t[sl]; sWgt[tid] = list_w[sl]; }
      else               { sTok[tid] = list_t[beg]; sWgt[tid] = 0.f; }
    }
    __syncthreads();
    int tokA[3];
    #pragma unroll
    for (int mf = 0; mf < 3; ++mf) tokA[mf] = sTok[wm * 48 + mf * 16 + (lane & 15)];

    float rg[4][8], ru[4][8];
    short8 rA[3][3][2];
    f32x4 accg[3][2] = {}; f32x4 accu[3][2] = {};

    // prologue: A0,A1 first (oldest), then B0..B3; write tile0; barrier.
    GU_ISSUE_A(0, rA[0]); GU_ISSUE_A(1, rA[1]);
    GU_ISSUE_B(0, rg[0], ru[0]); GU_ISSUE_B(1, rg[1], ru[1]);
    GU_ISSUE_B(2, rg[2], ru[2]); GU_ISSUE_B(3, rg[3], ru[3]);
    GU_WRITE_B(0, rg[0], ru[0]);
    BARRIER();

    #pragma unroll 1
    for (int t = 0; t < 24; t += 12){
      GU_BODY(t + 0,  0, 1, 1, 1);  GU_BODY(t + 1,  1, 1, 1, 1);
      GU_BODY(t + 2,  2, 1, 1, 1);  GU_BODY(t + 3,  3, 1, 1, 1);
      GU_BODY(t + 4,  4, 1, 1, 1);  GU_BODY(t + 5,  5, 1, 1, 1);
      GU_BODY(t + 6,  6, 1, 1, 1);  GU_BODY(t + 7,  7, 1, 1, 1);
      GU_BODY(t + 8,  8, 1, 1, 1);  GU_BODY(t + 9,  9, 1, 1, 1);
      GU_BODY(t + 10, 10, 1, 1, 1); GU_BODY(t + 11, 11, 1, 1, 1);
    }
    GU_BODY(24, 0, 1, 1, 1);  GU_BODY(25, 1, 1, 1, 1);
    GU_BODY(26, 2, 1, 1, 1);  GU_BODY(27, 3, 1, 1, 1);   // issues B31 (last)
    GU_BODY(28, 4, 1, 0, 1);  GU_BODY(29, 5, 1, 0, 1);   // A31 (last)
    GU_BODY(30, 6, 0, 0, 1);                              // writes tile 31
    GU_MFMA(1, rA[1]);                                    // body 31: MFMA only

    // epilogue: SwiGLU * routing weight -> bf16
    #pragma unroll
    for (int mf = 0; mf < 3; ++mf){
      #pragma unroll
      for (int rr = 0; rr < 4; ++rr){
        int r = wm * 48 + mf * 16 + ((lane >> 4) << 2) + rr;
        if (m0 + r < n_e){
          int slot = beg + m0 + r;
          float wgt = sWgt[r];
          #pragma unroll
          for (int nf = 0; nf < 2; ++nf){
            float g = accg[mf][nf][rr], u = accu[mf][nf][rr];
            float h = (g / (1.f + expf(-g))) * u * wgt;
            act[(size_t)slot * INTER + i0 + wn * 32 + nf * 16 + (lane & 15)] = f2bf(h);
          }
        }
      }
    }
  }
}

// ---------------- kernel 6: down-proj GEMM ----------------
// R2 geometry: BM=192, BN=128, BK=64, KT=12; depth-4 B sets, A 2-ahead, 2 LDS bufs.
__global__ __launch_bounds__(512) void k_down(
    const unsigned short* __restrict__ act, const float* __restrict__ wd,
    const int* __restrict__ offs, const int* __restrict__ list_t,
    float* __restrict__ contrib, float* __restrict__ out, int atomicMode){
  int bid = blockIdx.x;                   // 1024 = 64 e x 16 nb, XCD-colocated per e
  int xcd = bid & 7, idx = bid >> 3;      // idx 0..127
  int e  = (idx >> 4) * 8 + xcd;
  int n0 = (idx & 15) * 128;
  int beg = offs[e], n_e = offs[e + 1] - beg;
  if (n_e <= 0) return;
  int tid = threadIdx.x, lane = tid & 63, wid = tid >> 6;
  int wm = wid & 3, wn = wid >> 2;        // 48-row m-quarter, 64-col n-half

  __shared__ unsigned short lB[2][128 * 64]; // [buf][h*64k] swizzled, 32 KB
  __shared__ int sTok[192];

  int bh = tid & 127, bg = tid >> 7;
  int hswz = (bh & 7) << 4;
  const float* dBase = wd + (size_t)e * INTER * HID + n0 + bh;

#define DN_ISSUE_B(T, rb_) { \
    const float* _p = dBase + (size_t)((T) * 64 + bg * 8) * HID; \
    _Pragma("unroll") for (int j = 0; j < 8; ++j){ \
      rb_[j] = _p[(size_t)j * HID]; rb_[8 + j] = _p[(size_t)(j + 32) * HID]; } }

#define DN_WRITE_B(buf, rb_) { \
    uint4 _p; \
    _p.x = f2bf(rb_[0]) | ((unsigned)f2bf(rb_[1]) << 16); \
    _p.y = f2bf(rb_[2]) | ((unsigned)f2bf(rb_[3]) << 16); \
    _p.z = f2bf(rb_[4]) | ((unsigned)f2bf(rb_[5]) << 16); \
    _p.w = f2bf(rb_[6]) | ((unsigned)f2bf(rb_[7]) << 16); \
    *(uint4*)((char*)&lB[buf][0] + bh * 128 + ((bg * 16) ^ hswz)) = _p; \
    _p.x = f2bf(rb_[8])  | ((unsigned)f2bf(rb_[9])  << 16); \
    _p.y = f2bf(rb_[10]) | ((unsigned)f2bf(rb_[11]) << 16); \
    _p.z = f2bf(rb_[12]) | ((unsigned)f2bf(rb_[13]) << 16); \
    _p.w = f2bf(rb_[14]) | ((unsigned)f2bf(rb_[15]) << 16); \
    *(uint4*)((char*)&lB[buf][0] + bh * 128 + ((bg * 16 + 64) ^ hswz)) = _p; }

#define DN_ISSUE_A(T, ra_) { \
    int _kk = (T) * 64 + ((lane >> 4) << 3); \
    _Pragma("unroll") for (int mf = 0; mf < 3; ++mf){ \
      const unsigned short* _ap = act + (size_t)aslot[mf] * INTER + _kk; \
      ra_[mf][0] = *(const short8*)_ap; \
      ra_[mf][1] = *(const short8*)(_ap + 32); } }

#define DN_MFMA(buf, ra_) { \
    _Pragma("unroll") for (int ks = 0; ks < 2; ++ks){ \
      short8 _bf[4]; \
      _Pragma("unroll") for (int nf = 0; nf < 4; ++nf){ \
        int _il = wn * 64 + nf * 16 + (lane & 15); \
        int _kb = (ks * 64 + ((lane >> 4) << 4)) ^ ((_il & 7) << 4); \
        _bf[nf] = *(const short8*)((const char*)&lB[buf][0] + _il * 128 + _kb); } \
      _Pragma("unroll") for (int mf = 0; mf < 3; ++mf) \
        _Pragma("unroll") for (int nf = 0; nf < 4; ++nf) \
          acc[mf][nf] = __builtin_amdgcn_mfma_f32_16x16x32_bf16(ra_[mf][ks], _bf[nf], acc[mf][nf], 0, 0, 0); } }

#define DN_BODY(T, K, DA, DB, DW) { \
    if (DA) DN_ISSUE_A((T) + 2, rA[((K) + 2) % 3]); \
    if (DB) DN_ISSUE_B((T) + 4, rb[(K) % 4]); \
    DN_MFMA((K) & 1, rA[(K) % 3]); \
    if (DW) DN_WRITE_B(((K) + 1) & 1, rb[((K) + 1) % 4]); \
    BARRIER(); }

  for (int m0 = 0; m0 < n_e; m0 += 192){
    __syncthreads();
    if (tid < 192){
      int sl = beg + m0 + tid;
      sTok[tid] = (m0 + tid < n_e) ? list_t[sl] : 0;
    }
    __syncthreads();
    int aslot[3];
    #pragma unroll
    for (int mf = 0; mf < 3; ++mf){
      int r = wm * 48 + mf * 16 + (lane & 15);
      aslot[mf] = (m0 + r < n_e) ? (beg + m0 + r) : beg;
    }
    float rb[4][16];
    short8 rA[3][3][2];
    f32x4 acc[3][4] = {};

    DN_ISSUE_A(0, rA[0]); DN_ISSUE_A(1, rA[1]);
    DN_ISSUE_B(0, rb[0]); DN_ISSUE_B(1, rb[1]);
    DN_ISSUE_B(2, rb[2]); DN_ISSUE_B(3, rb[3]);
    DN_WRITE_B(0, rb[0]);
    BARRIER();

    DN_BODY(0,  0, 1, 1, 1);  DN_BODY(1,  1, 1, 1, 1);
    DN_BODY(2,  2, 1, 1, 1);  DN_BODY(3,  3, 1, 1, 1);
    DN_BODY(4,  4, 1, 1, 1);  DN_BODY(5,  5, 1, 1, 1);
    DN_BODY(6,  6, 1, 1, 1);  DN_BODY(7,  7, 1, 1, 1);   // issues B11 (last)
    DN_BODY(8,  8, 1, 0, 1);  DN_BODY(9,  9, 1, 0, 1);   // A11 (last)
    DN_BODY(10, 10, 0, 0, 1);                             // writes tile 11
    DN_MFMA(1, rA[2]);                                    // body 11: MFMA only

    #pragma unroll
    for (int mf = 0; mf < 3; ++mf){
      #pragma unroll
      for (int rr = 0; rr < 4; ++rr){
        int r = wm * 48 + mf * 16 + ((lane >> 4) << 2) + rr;
        if (m0 + r < n_e){
          int slot = beg + m0 + r;
          #pragma unroll
          for (int nf = 0; nf < 4; ++nf){
            float v = acc[mf][nf][rr];
            int h = n0 + wn * 64 + nf * 16 + (lane & 15);
            if (atomicMode) atomicAdd(&out[(size_t)sTok[r] * HID + h], v);
            else            contrib[(size_t)slot * HID + h] = v;
          }
        }
      }
    }
  }
}

// ---------------- kernel 7: deterministic 8-way combine ----------------
__global__ void k_reduce(const float* __restrict__ contrib, const int* __restrict__ slot_of,
                         float* __restrict__ out){
  int bx = blockIdx.x;
  int t = bx >> 1, seg = bx & 1, tid = threadIdx.x;
  __shared__ int ss[TOPK];
  if (tid < TOPK) ss[tid] = slot_of[t * TOPK + tid];
  __syncthreads();
  int h = (seg * 256 + tid) * 4;
  f32x4 s = {0.f, 0.f, 0.f, 0.f};
  #pragma unroll
  for (int k = 0; k < TOPK; ++k){
    f32x4 v = *(const f32x4*)(contrib + (size_t)ss[k] * HID + h);
    s += v;
  }
  *(f32x4*)(out + (size_t)t * HID + h) = s;
}

extern "C" void kernel_launch(void* const* d_in, const int* in_sizes, int n_in,
                              void* d_out, int out_size, void* d_ws, size_t ws_size,
                              hipStream_t stream){
  const float* x   = (const float*)d_in[0];
  const float* gw  = (const float*)d_in[1];
  const float* wgp = (const float*)d_in[2];
  const float* wup = (const float*)d_in[3];
  const float* wdp = (const float*)d_in[4];
  float* out = (float*)d_out;
  char* ws = (char*)d_ws;

  int*   top_idx = (int*)  (ws + 0);
  float* top_w   = (float*)(ws + 32768);
  int*   offs    = (int*)  (ws + 65536);
  int*   list_t  = (int*)  (ws + 69632);
  float* list_w  = (float*)(ws + 102400);
  int*   slot_of = (int*)  (ws + 135168);
  unsigned short* xbf = (unsigned short*)(ws + 167936);             // 4 MB
  unsigned short* act = (unsigned short*)(ws + 167936 + 4194304);   // 12 MB
  float* contrib = (float*)(ws + 167936 + 4194304 + 12582912);      // 64 MB
  size_t need_full = (size_t)167936 + 4194304 + 12582912 + 67108864;
  int atomicMode = (ws_size < need_full) ? 1 : 0;

  k_convert_x<<<1024, 256, 0, stream>>>(x, xbf);
  k_router   <<<1024, 256, 0, stream>>>(x, gw, top_idx, top_w);
  k_hist     <<<1,    256, 0, stream>>>(top_idx, offs);
  k_compact  <<<64,   256, 0, stream>>>(top_idx, top_w, offs, list_t, list_w, slot_of);
  k_gateup   <<<768,  512, 0, stream>>>(xbf, wgp, wup, offs, list_t, list_w, act);
  if (atomicMode){
    hipMemsetAsync(d_out, 0, (size_t)out_size * sizeof(float), stream);
    k_down  <<<1024, 512, 0, stream>>>(act, wdp, offs, list_t, contrib, out, 1);
  } else {
    k_down  <<<1024, 512, 0, stream>>>(act, wdp, offs, list_t, contrib, out, 0);
    k_reduce<<<2048, 256, 0, stream>>>(contrib, slot_of, out);
  }
}